// Round 3
// baseline (341.962 us; speedup 1.0000x reference)
//
#include <hip/hip_runtime.h>
#include <stdint.h>

typedef unsigned short u16;
typedef _Float16 f16;
typedef __attribute__((ext_vector_type(2))) _Float16 f16x2;
typedef __attribute__((ext_vector_type(8))) _Float16 f16x8;
typedef __attribute__((ext_vector_type(4))) float f32x4;
typedef __attribute__((ext_vector_type(4))) int i32x4;

__device__ __forceinline__ int pk2(float a, float b) {
  return __builtin_bit_cast(int, __builtin_amdgcn_cvt_pkrtz(a, b));
}

// 8 int4 values (two i32x4, values 0..15) -> f16x8 weights (q - z) * s.
// (q | 0x6400) is f16 1024+q EXACTLY; z integer -> subtract is exact; one rounded mul.
__device__ __forceinline__ f16x8 dq8(i32x4 qa, i32x4 qb, f16x2 z2, f16x2 s2) {
  unsigned u0 = (unsigned)qa[0] | ((unsigned)qa[1] << 16) | 0x64006400u;
  unsigned u1 = (unsigned)qa[2] | ((unsigned)qa[3] << 16) | 0x64006400u;
  unsigned u2 = (unsigned)qb[0] | ((unsigned)qb[1] << 16) | 0x64006400u;
  unsigned u3 = (unsigned)qb[2] | ((unsigned)qb[3] << 16) | 0x64006400u;
  f16x2 w0 = (__builtin_bit_cast(f16x2, u0) - z2) * s2;
  f16x2 w1 = (__builtin_bit_cast(f16x2, u1) - z2) * s2;
  f16x2 w2 = (__builtin_bit_cast(f16x2, u2) - z2) * s2;
  f16x2 w3 = (__builtin_bit_cast(f16x2, u3) - z2) * s2;
  i32x4 t = {__builtin_bit_cast(int, w0), __builtin_bit_cast(int, w1),
             __builtin_bit_cast(int, w2), __builtin_bit_cast(int, w3)};
  return __builtin_bit_cast(f16x8, t);
}

// ---------------- x fp32 -> fp16 ----------------
__global__ __launch_bounds__(256) void cvt_x(const float* __restrict__ src,
                                             i32x4* __restrict__ dst, int n8) {
  int t = blockIdx.x * 256 + threadIdx.x;
  if (t >= n8) return;
  f32x4 a = ((const f32x4*)src)[2 * t];
  f32x4 b = ((const f32x4*)src)[2 * t + 1];
  i32x4 o = {pk2(a[0], a[1]), pk2(a[2], a[3]), pk2(b[0], b[1]), pk2(b[2], b[3])};
  dst[t] = o;
}

// ---------------- GEMM1: h = relu(x @ w1^T + b1) + out-init tail ----------------
// M=512,N=8192,K=2048. No LDS, no barriers. Wave=64x64 (4x4 16x16x32 frags),
// block = 2x2 waves = 128x128, grid (64,4)=256 blocks.
__global__ __launch_bounds__(256) void gemm1(const f16* __restrict__ X,
                                             const int* __restrict__ Q,
                                             const float* __restrict__ S,
                                             const float* __restrict__ Z,
                                             const float* __restrict__ b1,
                                             const float* __restrict__ b2,
                                             f16* __restrict__ H,
                                             float* __restrict__ out) {
  const int K = 2048, N = 8192, G = 16;
  const int tid = threadIdx.x, wave = tid >> 6, lane = tid & 63;
  const int quad = lane >> 4, l15 = lane & 15;
  const int m0 = blockIdx.y << 7, n0 = blockIdx.x << 7;
  const int wm = (wave >> 1) << 6, wn = (wave & 1) << 6;

  const f16* aP[4];
  const int* qP[4];
  int nrow[4];
#pragma unroll
  for (int i = 0; i < 4; i++) aP[i] = X + (size_t)(m0 + wm + i * 16 + l15) * K + quad * 8;
#pragma unroll
  for (int j = 0; j < 4; j++) {
    nrow[j] = n0 + wn + j * 16 + l15;
    qP[j] = Q + (size_t)nrow[j] * K + quad * 8;
  }

  // prefetch k=0
  i32x4 qa[4], qb[4];
  f16x8 af[4];
  f16x2 s2[4], z2[4];
#pragma unroll
  for (int j = 0; j < 4; j++) {
    qa[j] = *(const i32x4*)(qP[j]);
    qb[j] = *(const i32x4*)(qP[j] + 4);
    float s = S[nrow[j] * G], z = Z[nrow[j] * G];
    f16 sh = (f16)s, zh = (f16)(1024.f + z);
    s2[j] = (f16x2){sh, sh};
    z2[j] = (f16x2){zh, zh};
  }
#pragma unroll
  for (int i = 0; i < 4; i++) af[i] = *(const f16x8*)(aP[i]);

  f32x4 acc[4][4];
#pragma unroll
  for (int i = 0; i < 4; i++)
#pragma unroll
    for (int j = 0; j < 4; j++) acc[i][j] = (f32x4){0.f, 0.f, 0.f, 0.f};

#pragma unroll 2
  for (int k = 0; k < K; k += 32) {
    i32x4 cqa[4], cqb[4];
    f16x8 caf[4];
    f16x2 cs2[4], cz2[4];
#pragma unroll
    for (int j = 0; j < 4; j++) { cqa[j] = qa[j]; cqb[j] = qb[j]; cs2[j] = s2[j]; cz2[j] = z2[j]; }
#pragma unroll
    for (int i = 0; i < 4; i++) caf[i] = af[i];
    if (k + 32 < K) {  // uniform: prefetch next k-step (no barriers -> stays in flight)
#pragma unroll
      for (int j = 0; j < 4; j++) {
        qa[j] = *(const i32x4*)(qP[j] + k + 32);
        qb[j] = *(const i32x4*)(qP[j] + k + 36);
      }
#pragma unroll
      for (int i = 0; i < 4; i++) af[i] = *(const f16x8*)(aP[i] + k + 32);
      if (((k + 32) & 127) == 0) {
        const int g = (k + 32) >> 7;
#pragma unroll
        for (int j = 0; j < 4; j++) {
          float s = S[nrow[j] * G + g], z = Z[nrow[j] * G + g];
          f16 sh = (f16)s, zh = (f16)(1024.f + z);
          s2[j] = (f16x2){sh, sh};
          z2[j] = (f16x2){zh, zh};
        }
      }
    }
    f16x8 bf[4];
#pragma unroll
    for (int j = 0; j < 4; j++) bf[j] = dq8(cqa[j], cqb[j], cz2[j], cs2[j]);
#pragma unroll
    for (int i = 0; i < 4; i++)
#pragma unroll
      for (int j = 0; j < 4; j++)
        acc[i][j] = __builtin_amdgcn_mfma_f32_16x16x32_f16(caf[i], bf[j], acc[i][j], 0, 0, 0);
  }

  // epilogue: C/D col=lane&15, row=quad*4+reg; bias+relu, f16 store
#pragma unroll
  for (int i = 0; i < 4; i++)
#pragma unroll
    for (int j = 0; j < 4; j++) {
      const int col = n0 + wn + j * 16 + l15;
      const float bv = b1[col];
#pragma unroll
      for (int r = 0; r < 4; r++) {
        const int row = m0 + wm + i * 16 + quad * 4 + r;
        float v = acc[i][j][r] + bv;
        v = v > 0.f ? v : 0.f;
        H[(size_t)row * N + col] = (f16)v;
      }
    }

  // tail: init out (poisoned每call) with b2 broadcast; gemm2 (next launch) accumulates.
  {
    const int lin = (int)(blockIdx.y * gridDim.x + blockIdx.x);  // 0..255
    const int base = lin * 4096 + tid * 16;                      // 512*2048/256 = 4096/block
#pragma unroll
    for (int e = 0; e < 4; e++) {
      const int idx = base + e * 4;
      *(f32x4*)(out + idx) = *(const f32x4*)(b2 + (idx & 2047));
    }
  }
}

// ---------------- GEMM2: out += h @ w2^T (split-K=4 atomic) ----------------
// M=512,N=2048,K=8192. Wave=64x64, block 2x2 waves=128x128, grid (16,4,4)=256.
__global__ __launch_bounds__(256) void gemm2(const f16* __restrict__ Hm,
                                             const int* __restrict__ Q,
                                             const float* __restrict__ S,
                                             const float* __restrict__ Z,
                                             float* __restrict__ out) {
  const int K = 8192, N = 2048, G = 64, KCH = 2048;
  const int tid = threadIdx.x, wave = tid >> 6, lane = tid & 63;
  const int quad = lane >> 4, l15 = lane & 15;
  const int m0 = blockIdx.y << 7, n0 = blockIdx.x << 7;
  const int kStart = blockIdx.z << 11;
  const int wm = (wave >> 1) << 6, wn = (wave & 1) << 6;

  const f16* aP[4];
  const int* qP[4];
  int nrow[4];
#pragma unroll
  for (int i = 0; i < 4; i++)
    aP[i] = Hm + (size_t)(m0 + wm + i * 16 + l15) * K + kStart + quad * 8;
#pragma unroll
  for (int j = 0; j < 4; j++) {
    nrow[j] = n0 + wn + j * 16 + l15;
    qP[j] = Q + (size_t)nrow[j] * K + kStart + quad * 8;
  }

  i32x4 qa[4], qb[4];
  f16x8 af[4];
  f16x2 s2[4], z2[4];
  const int g0 = kStart >> 7;
#pragma unroll
  for (int j = 0; j < 4; j++) {
    qa[j] = *(const i32x4*)(qP[j]);
    qb[j] = *(const i32x4*)(qP[j] + 4);
    float s = S[nrow[j] * G + g0], z = Z[nrow[j] * G + g0];
    f16 sh = (f16)s, zh = (f16)(1024.f + z);
    s2[j] = (f16x2){sh, sh};
    z2[j] = (f16x2){zh, zh};
  }
#pragma unroll
  for (int i = 0; i < 4; i++) af[i] = *(const f16x8*)(aP[i]);

  f32x4 acc[4][4];
#pragma unroll
  for (int i = 0; i < 4; i++)
#pragma unroll
    for (int j = 0; j < 4; j++) acc[i][j] = (f32x4){0.f, 0.f, 0.f, 0.f};

#pragma unroll 2
  for (int k = 0; k < KCH; k += 32) {
    i32x4 cqa[4], cqb[4];
    f16x8 caf[4];
    f16x2 cs2[4], cz2[4];
#pragma unroll
    for (int j = 0; j < 4; j++) { cqa[j] = qa[j]; cqb[j] = qb[j]; cs2[j] = s2[j]; cz2[j] = z2[j]; }
#pragma unroll
    for (int i = 0; i < 4; i++) caf[i] = af[i];
    if (k + 32 < KCH) {
#pragma unroll
      for (int j = 0; j < 4; j++) {
        qa[j] = *(const i32x4*)(qP[j] + k + 32);
        qb[j] = *(const i32x4*)(qP[j] + k + 36);
      }
#pragma unroll
      for (int i = 0; i < 4; i++) af[i] = *(const f16x8*)(aP[i] + k + 32);
      if (((k + 32) & 127) == 0) {
        const int g = (kStart + k + 32) >> 7;
#pragma unroll
        for (int j = 0; j < 4; j++) {
          float s = S[nrow[j] * G + g], z = Z[nrow[j] * G + g];
          f16 sh = (f16)s, zh = (f16)(1024.f + z);
          s2[j] = (f16x2){sh, sh};
          z2[j] = (f16x2){zh, zh};
        }
      }
    }
    f16x8 bf[4];
#pragma unroll
    for (int j = 0; j < 4; j++) bf[j] = dq8(cqa[j], cqb[j], cz2[j], cs2[j]);
#pragma unroll
    for (int i = 0; i < 4; i++)
#pragma unroll
      for (int j = 0; j < 4; j++)
        acc[i][j] = __builtin_amdgcn_mfma_f32_16x16x32_f16(caf[i], bf[j], acc[i][j], 0, 0, 0);
  }

#pragma unroll
  for (int i = 0; i < 4; i++)
#pragma unroll
    for (int j = 0; j < 4; j++) {
      const int col = n0 + wn + j * 16 + l15;
#pragma unroll
      for (int r = 0; r < 4; r++) {
        const int row = m0 + wm + i * 16 + quad * 4 + r;
        atomicAdd(out + (size_t)row * N + col, acc[i][j][r]);
      }
    }
}

// ---------------- launch ----------------
extern "C" void kernel_launch(void* const* d_in, const int* in_sizes, int n_in,
                              void* d_out, int out_size, void* d_ws, size_t ws_size,
                              hipStream_t stream) {
  const float* x = (const float*)d_in[0];
  const int* q1 = (const int*)d_in[1];
  const float* s1 = (const float*)d_in[2];
  const float* z1 = (const float*)d_in[3];
  const float* b1 = (const float*)d_in[4];
  const int* q2 = (const int*)d_in[5];
  const float* s2 = (const float*)d_in[6];
  const float* z2 = (const float*)d_in[7];
  const float* b2 = (const float*)d_in[8];
  float* out = (float*)d_out;

  char* ws = (char*)d_ws;
  f16* xh = (f16*)ws;                               // 2 MB: x f16 [512][2048]
  f16* h = (f16*)(ws + (size_t)2 * 1024 * 1024);    // 8 MB: h f16 [512][8192]

  cvt_x<<<512, 256, 0, stream>>>(x, (i32x4*)xh, 512 * 2048 / 8);
  gemm1<<<dim3(64, 4), 256, 0, stream>>>(xh, q1, s1, z1, b1, b2, h, out);
  gemm2<<<dim3(16, 4, 4), 256, 0, stream>>>(h, q2, s2, z2, out);
}

// Round 5
// 290.684 us; speedup vs baseline: 1.1764x; 1.1764x over previous
//
#include <hip/hip_runtime.h>
#include <stdint.h>

typedef unsigned short u16;
typedef _Float16 f16;
typedef __attribute__((ext_vector_type(2))) _Float16 f16x2;
typedef __attribute__((ext_vector_type(8))) _Float16 f16x8;
typedef __attribute__((ext_vector_type(4))) float f32x4;
typedef __attribute__((ext_vector_type(4))) int i32x4;

// LDS: As dbuf 2x8KB (64B rows, XOR-swizzled k-chunks), Bs dbuf 2x10240B (rows
// padded to 40 f16 = 80B -> ~2-way max on b128 ops). Total 36864B, 2 blocks/CU.
#define BSTRIDE 40

#define GLD16(g, l)                                                         \
  __builtin_amdgcn_global_load_lds(                                         \
      (const __attribute__((address_space(1))) void*)(g),                   \
      (__attribute__((address_space(3))) void*)(l), 16, 0, 0)

// Drain ALL outstanding vmem (this wave's prev-iter GLD16s + q prefetch regs).
#define DRAIN_VM() asm volatile("s_waitcnt vmcnt(0)" ::: "memory")
// Barrier draining LDS only; no vmem load needs to cross an s_barrier (all
// next-iter loads are issued AFTER the barrier, drained one iter later).
#define BARRIER_LGKM() asm volatile("s_waitcnt lgkmcnt(0)\n\ts_barrier" ::: "memory")

__device__ __forceinline__ int pk2(float a, float b) {
  return __builtin_bit_cast(int, __builtin_amdgcn_cvt_pkrtz(a, b));
}

// 8 int4 (two i32x4, 0..15) -> (q - z) * s in f16, one rounding total:
// (q | 0x6400) is f16 1024+q exactly; integer zh subtract exact; one rounded mul.
__device__ __forceinline__ f16x8 dq8(i32x4 qa, i32x4 qb, f16x2 z2, f16x2 s2) {
  unsigned u0 = (unsigned)qa[0] | ((unsigned)qa[1] << 16) | 0x64006400u;
  unsigned u1 = (unsigned)qa[2] | ((unsigned)qa[3] << 16) | 0x64006400u;
  unsigned u2 = (unsigned)qb[0] | ((unsigned)qb[1] << 16) | 0x64006400u;
  unsigned u3 = (unsigned)qb[2] | ((unsigned)qb[3] << 16) | 0x64006400u;
  f16x2 w0 = (__builtin_bit_cast(f16x2, u0) - z2) * s2;
  f16x2 w1 = (__builtin_bit_cast(f16x2, u1) - z2) * s2;
  f16x2 w2 = (__builtin_bit_cast(f16x2, u2) - z2) * s2;
  f16x2 w3 = (__builtin_bit_cast(f16x2, u3) - z2) * s2;
  i32x4 t = {__builtin_bit_cast(int, w0), __builtin_bit_cast(int, w1),
             __builtin_bit_cast(int, w2), __builtin_bit_cast(int, w3)};
  return __builtin_bit_cast(f16x8, t);
}

// ---------------- kernel 1: x -> f16, out <- b2 broadcast ----------------
__global__ __launch_bounds__(256) void cvt_init(const float* __restrict__ x,
                                                const float* __restrict__ b2,
                                                f16* __restrict__ xh,
                                                float* __restrict__ out) {
  const int g = blockIdx.x * 256 + threadIdx.x;  // 131072 threads x 8 elems
  f32x4 a = ((const f32x4*)x)[2 * g];
  f32x4 b = ((const f32x4*)x)[2 * g + 1];
  i32x4 o = {pk2(a[0], a[1]), pk2(a[2], a[3]), pk2(b[0], b[1]), pk2(b[2], b[3])};
  ((i32x4*)xh)[g] = o;
  const int oi = g * 8;
  *(f32x4*)(out + oi) = *(const f32x4*)(b2 + (oi & 2047));
  *(f32x4*)(out + oi + 4) = *(const f32x4*)(b2 + ((oi + 4) & 2047));
}

// ---------------- kernel 2: h = relu(xh @ w1^T + b1) ----------------
// M=512,N=8192,K=2048. Tile 64x128, grid 512 (2 blocks/CU). bid = mt*64+nt:
// 8 q1-sharers are 64 apart -> same XCD L2. Wave: 32(m)x64(n) = 2x4 frags.
__global__ __launch_bounds__(256, 2) void gemm1_k(const f16* __restrict__ X,
                                                  const int* __restrict__ Q,
                                                  const float* __restrict__ S,
                                                  const float* __restrict__ Z,
                                                  const float* __restrict__ b1,
                                                  f16* __restrict__ H) {
  __shared__ char smem[36864];
  f16* As0 = (f16*)smem;
  f16* As1 = (f16*)(smem + 8192);
  f16* Bs0 = (f16*)(smem + 16384);
  f16* Bs1 = (f16*)(smem + 16384 + 10240);
  const int tid = threadIdx.x, bid = blockIdx.x;
  const int wave = tid >> 6, lane = tid & 63, quad = lane >> 4, l15 = lane & 15;
  const int K = 2048, G = 16;
  const int mt = bid >> 6, nt = bid & 63;
  const int m0 = mt << 6, n0 = nt << 7;
  const int wm = (wave >> 1) << 5, wn = (wave & 1) << 6;

  // A staging: wave w stages rows m0+16w..+15. Lane i -> row r=i>>2, XOR-swizzled
  // k-chunk c=(i&3)^(r&3) (reader uses chunk q^(row&3)) -> 4 bank-starts not 2.
  const int sr = lane >> 2, sc = (lane & 3) ^ (sr & 3);
  const f16* asrc = X + (size_t)(m0 + 16 * wave + sr) * K + sc * 8;
  const int adoff = wave * 1024;  // bytes; global row R lands at As + R*64

  // B staging: row brow (0..127), half bhf covers k-ints bhf*16..+15.
  const int brow = tid >> 1, bhf = tid & 1;
  const int grow = n0 + brow;
  const int* qp = Q + (size_t)grow * K + bhf * 16;
  const float* sp = S + grow * G;
  const float* zp = Z + grow * G;

  GLD16(asrc, (char*)As0 + adoff);
  i32x4 nb0 = *(const i32x4*)(qp);
  i32x4 nb1 = *(const i32x4*)(qp + 4);
  i32x4 nb2 = *(const i32x4*)(qp + 8);
  i32x4 nb3 = *(const i32x4*)(qp + 12);
  float ns = sp[0], nz = zp[0];

  f32x4 acc[2][4];
#pragma unroll
  for (int i = 0; i < 2; i++)
#pragma unroll
    for (int j = 0; j < 4; j++) acc[i][j] = (f32x4){0.f, 0.f, 0.f, 0.f};

#pragma unroll 2
  for (int k = 0; k < K; k += 32) {
    const int buf = (k >> 5) & 1;
    f16* AsB = buf ? As1 : As0;
    f16* BsB = buf ? Bs1 : Bs0;
    DRAIN_VM();  // own GLD16(buf) + nb regs landed; all waves drain before barrier
    i32x4 c0 = nb0, c1 = nb1, c2 = nb2, c3 = nb3;
    const f16 sh = (f16)ns, zh = (f16)(1024.f + nz);
    const f16x2 s2v = {sh, sh}, z2v = {zh, zh};
    f16x8 w0 = dq8(c0, c1, z2v, s2v);
    f16x8 w1 = dq8(c2, c3, z2v, s2v);
    *(f16x8*)&BsB[brow * BSTRIDE + bhf * 16] = w0;
    *(f16x8*)&BsB[brow * BSTRIDE + bhf * 16 + 8] = w1;
    BARRIER_LGKM();
    f16x8 af[2], bf[4];
#pragma unroll
    for (int i = 0; i < 2; i++) {
      const int R = wm + i * 16 + l15;
      af[i] = *(const f16x8*)&AsB[R * 32 + ((quad ^ (R & 3)) << 3)];
    }
#pragma unroll
    for (int j = 0; j < 4; j++)
      bf[j] = *(const f16x8*)&BsB[(wn + j * 16 + l15) * BSTRIDE + quad * 8];
    if (k + 32 < K) {  // uniform; next-iter loads, never cross an s_barrier
      GLD16(asrc + k + 32, (char*)(buf ? As0 : As1) + adoff);
      nb0 = *(const i32x4*)(qp + k + 32);
      nb1 = *(const i32x4*)(qp + k + 36);
      nb2 = *(const i32x4*)(qp + k + 40);
      nb3 = *(const i32x4*)(qp + k + 44);
      const int g = (k + 32) >> 7;
      ns = sp[g];
      nz = zp[g];
    }
#pragma unroll
    for (int i = 0; i < 2; i++)
#pragma unroll
      for (int j = 0; j < 4; j++)
        acc[i][j] = __builtin_amdgcn_mfma_f32_16x16x32_f16(af[i], bf[j], acc[i][j], 0, 0, 0);
  }

  // C/D: col=lane&15, row=quad*4+reg; bias+relu, f16 store
#pragma unroll
  for (int i = 0; i < 2; i++)
#pragma unroll
    for (int j = 0; j < 4; j++) {
      const int col = n0 + wn + j * 16 + l15;
      const float bv = b1[col];
#pragma unroll
      for (int r = 0; r < 4; r++) {
        const int row = m0 + wm + i * 16 + quad * 4 + r;
        float v = acc[i][j][r] + bv;
        v = v > 0.f ? v : 0.f;
        H[(size_t)row * 8192 + col] = (f16)v;
      }
    }
}

// ---------------- kernel 3: out += h @ w2^T (split-K=8, atomic) ----------------
// M=512,N=2048,K=8192. Tile 128x128, kChunk=1024, grid 512: bid = mt*128+nt*8+zb;
// 4 q2-panel sharers are 128 apart -> same XCD.
__global__ __launch_bounds__(256, 2) void gemm2_k(const f16* __restrict__ Hm,
                                                  const int* __restrict__ Q,
                                                  const float* __restrict__ S,
                                                  const float* __restrict__ Z,
                                                  float* __restrict__ out) {
  __shared__ char smem[36864];
  f16* As0 = (f16*)smem;
  f16* As1 = (f16*)(smem + 8192);
  f16* Bs0 = (f16*)(smem + 16384);
  f16* Bs1 = (f16*)(smem + 16384 + 10240);
  const int tid = threadIdx.x, bid = blockIdx.x;
  const int wave = tid >> 6, lane = tid & 63, quad = lane >> 4, l15 = lane & 15;
  const int K = 8192, G = 64;
  const int zb = bid & 7, nt = (bid >> 3) & 15, mt = bid >> 7;
  const int m0 = mt << 7, n0 = nt << 7;
  const int kStart = zb << 10;
  const int wm = (wave >> 1) << 6, wn = (wave & 1) << 6;

  // A staging: wave w stages rows m0+32w..+31 via 2 GLD16s ((r+16)&3 == r&3 so
  // the same swizzled column works for both).
  const int sr = lane >> 2, sc = (lane & 3) ^ (sr & 3);
  const f16* asrc = Hm + (size_t)(m0 + 32 * wave + sr) * K + kStart + sc * 8;
  const size_t arow16 = (size_t)16 * K;
  const int adoff = wave * 2048;

  const int brow = tid >> 1, bhf = tid & 1;
  const int grow = n0 + brow;
  const int* qp = Q + (size_t)grow * K + kStart + bhf * 16;
  const float* sp = S + grow * G;
  const float* zp = Z + grow * G;

  GLD16(asrc, (char*)As0 + adoff);
  GLD16(asrc + arow16, (char*)As0 + adoff + 1024);
  i32x4 nb0 = *(const i32x4*)(qp);
  i32x4 nb1 = *(const i32x4*)(qp + 4);
  i32x4 nb2 = *(const i32x4*)(qp + 8);
  i32x4 nb3 = *(const i32x4*)(qp + 12);
  float ns = sp[kStart >> 7], nz = zp[kStart >> 7];

  f32x4 acc[4][4];
#pragma unroll
  for (int i = 0; i < 4; i++)
#pragma unroll
    for (int j = 0; j < 4; j++) acc[i][j] = (f32x4){0.f, 0.f, 0.f, 0.f};

#pragma unroll 2
  for (int k = 0; k < 1024; k += 32) {
    const int buf = (k >> 5) & 1;
    f16* AsB = buf ? As1 : As0;
    f16* BsB = buf ? Bs1 : Bs0;
    DRAIN_VM();
    i32x4 c0 = nb0, c1 = nb1, c2 = nb2, c3 = nb3;
    const f16 sh = (f16)ns, zh = (f16)(1024.f + nz);
    const f16x2 s2v = {sh, sh}, z2v = {zh, zh};
    f16x8 w0 = dq8(c0, c1, z2v, s2v);
    f16x8 w1 = dq8(c2, c3, z2v, s2v);
    *(f16x8*)&BsB[brow * BSTRIDE + bhf * 16] = w0;
    *(f16x8*)&BsB[brow * BSTRIDE + bhf * 16 + 8] = w1;
    BARRIER_LGKM();
    f16x8 af[4], bf[4];
#pragma unroll
    for (int i = 0; i < 4; i++) {
      const int R = wm + i * 16 + l15;
      af[i] = *(const f16x8*)&AsB[R * 32 + ((quad ^ (R & 3)) << 3)];
    }
#pragma unroll
    for (int j = 0; j < 4; j++)
      bf[j] = *(const f16x8*)&BsB[(wn + j * 16 + l15) * BSTRIDE + quad * 8];
    if (k + 32 < 1024) {
      char* AsN = (char*)(buf ? As0 : As1);
      GLD16(asrc + k + 32, AsN + adoff);
      GLD16(asrc + k + 32 + arow16, AsN + adoff + 1024);
      nb0 = *(const i32x4*)(qp + k + 32);
      nb1 = *(const i32x4*)(qp + k + 36);
      nb2 = *(const i32x4*)(qp + k + 40);
      nb3 = *(const i32x4*)(qp + k + 44);
      const int g = (kStart + k + 32) >> 7;
      ns = sp[g];
      nz = zp[g];
    }
#pragma unroll
    for (int i = 0; i < 4; i++)
#pragma unroll
      for (int j = 0; j < 4; j++)
        acc[i][j] = __builtin_amdgcn_mfma_f32_16x16x32_f16(af[i], bf[j], acc[i][j], 0, 0, 0);
  }

#pragma unroll
  for (int i = 0; i < 4; i++)
#pragma unroll
    for (int j = 0; j < 4; j++) {
      const int col = n0 + wn + j * 16 + l15;
#pragma unroll
      for (int r = 0; r < 4; r++) {
        const int row = m0 + wm + i * 16 + quad * 4 + r;
        atomicAdd(out + (size_t)row * 2048 + col, acc[i][j][r]);
      }
    }
}

// ---------------- launch ----------------
extern "C" void kernel_launch(void* const* d_in, const int* in_sizes, int n_in,
                              void* d_out, int out_size, void* d_ws, size_t ws_size,
                              hipStream_t stream) {
  const float* x = (const float*)d_in[0];
  const int* q1 = (const int*)d_in[1];
  const float* s1 = (const float*)d_in[2];
  const float* z1 = (const float*)d_in[3];
  const float* b1 = (const float*)d_in[4];
  const int* q2 = (const int*)d_in[5];
  const float* s2 = (const float*)d_in[6];
  const float* z2 = (const float*)d_in[7];
  const float* b2 = (const float*)d_in[8];
  float* out = (float*)d_out;

  char* ws = (char*)d_ws;
  f16* xh = (f16*)ws;                              // 2 MB: x f16 [512][2048]
  f16* h = (f16*)(ws + (size_t)2 * 1024 * 1024);   // 8 MB: h f16 [512][8192]

  cvt_init<<<512, 256, 0, stream>>>(x, b2, xh, out);
  gemm1_k<<<512, 256, 0, stream>>>(xh, q1, s1, z1, b1, h);
  gemm2_k<<<512, 256, 0, stream>>>(h, q2, s2, z2, out);
}